// Round 1
// baseline (9042.287 us; speedup 1.0000x reference)
//
#include <hip/hip_runtime.h>
#include <stdint.h>

#define T_DIM 512
#define B_DIM 64
#define I_DIM 512
#define H_DIM 1024

typedef __attribute__((ext_vector_type(8))) short short8;
typedef __attribute__((ext_vector_type(4))) float f32x4;

__device__ __forceinline__ unsigned short f2bf(float f) {
    unsigned int u = __float_as_uint(f);
    unsigned int r = (u + 0x7FFFu + ((u >> 16) & 1u)) >> 16;
    return (unsigned short)r;
}
__device__ __forceinline__ float bf2f(unsigned short b) {
    return __uint_as_float(((unsigned int)b) << 16);
}
__device__ __forceinline__ short8 ld_frag(const unsigned short* p) {
    return *reinterpret_cast<const short8*>(p);
}

// ---------------- f32 -> bf16 convert, vectorized x4 ----------------
__global__ void conv_f2bf(const float* __restrict__ in, unsigned short* __restrict__ out, int n4) {
    int i = blockIdx.x * blockDim.x + threadIdx.x;
    int stride = gridDim.x * blockDim.x;
    for (int idx = i; idx < n4; idx += stride) {
        float4 v = reinterpret_cast<const float4*>(in)[idx];
        ushort4 o;
        o.x = f2bf(v.x); o.y = f2bf(v.y); o.z = f2bf(v.z); o.w = f2bf(v.w);
        reinterpret_cast<ushort4*>(out)[idx] = o;
    }
}

__global__ void bias_sum(const float* __restrict__ a, const float* __restrict__ b,
                         float* __restrict__ o, int n) {
    int i = blockIdx.x * blockDim.x + threadIdx.x;
    if (i < n) o[i] = a[i] + b[i];
}

// ---------------- GEMM: C[M,N] = A[M,K] @ W[N,K]^T + bias[N] ----------------
// 64x64 tile per workgroup, 4 waves (2x2), each wave 32x32 via 2x2 MFMA frags.
template <int OUT_BF16>
__global__ void gemm_bias(const unsigned short* __restrict__ A,
                          const unsigned short* __restrict__ W,
                          const float* __restrict__ bias,
                          void* __restrict__ Cout,
                          int M, int N, int K) {
    const int ntn = N >> 6;
    const int mt = blockIdx.x / ntn;
    const int nt = blockIdx.x % ntn;
    const int m_base = mt << 6, n_base = nt << 6;
    const int lane = threadIdx.x & 63;
    const int wave = threadIdx.x >> 6;
    const int wm = wave >> 1, wn = wave & 1;
    const int r0 = lane & 15;
    const int g  = lane >> 4;
    const int koff = g << 3;

    f32x4 acc[2][2];
    for (int i = 0; i < 2; i++)
        for (int j = 0; j < 2; j++)
            acc[i][j] = (f32x4)(0.f);

    const unsigned short* Arow0 = A + (size_t)(m_base + wm * 32 + r0) * K + koff;
    const unsigned short* Wrow0 = W + (size_t)(n_base + wn * 32 + r0) * K + koff;

    for (int k0 = 0; k0 < K; k0 += 32) {
        short8 a0 = ld_frag(Arow0 + k0);
        short8 a1 = ld_frag(Arow0 + (size_t)16 * K + k0);
        short8 b0 = ld_frag(Wrow0 + k0);
        short8 b1 = ld_frag(Wrow0 + (size_t)16 * K + k0);
        acc[0][0] = __builtin_amdgcn_mfma_f32_16x16x32_bf16(a0, b0, acc[0][0], 0, 0, 0);
        acc[0][1] = __builtin_amdgcn_mfma_f32_16x16x32_bf16(a0, b1, acc[0][1], 0, 0, 0);
        acc[1][0] = __builtin_amdgcn_mfma_f32_16x16x32_bf16(a1, b0, acc[1][0], 0, 0, 0);
        acc[1][1] = __builtin_amdgcn_mfma_f32_16x16x32_bf16(a1, b1, acc[1][1], 0, 0, 0);
    }

    for (int mi = 0; mi < 2; mi++) {
        for (int ni = 0; ni < 2; ni++) {
            for (int r = 0; r < 4; r++) {
                int row = m_base + wm * 32 + mi * 16 + g * 4 + r;
                int col = n_base + wn * 32 + ni * 16 + r0;
                float v = acc[mi][ni][r] + bias[col];
                if (OUT_BF16)
                    ((unsigned short*)Cout)[(size_t)row * N + col] = f2bf(v);
                else
                    ((float*)Cout)[(size_t)row * N + col] = v;
            }
        }
    }
}

// ---------------- RNN step (pipelined: layer0 at t=s, layer1 at t=s-1) ----------------
// Grid: 128 wgs x 256 thr. wg<64: layer0, 16 output cols each. wg>=64: layer1.
// Each wave handles 16 batch rows (4 waves x 16 = B=64).
__global__ void rnn_step(int s,
                         const unsigned short* __restrict__ xp0,
                         const unsigned short* __restrict__ whh0,
                         const unsigned short* __restrict__ wih1,
                         const unsigned short* __restrict__ whh1,
                         const float* __restrict__ bias1,
                         const unsigned short* __restrict__ hinit,
                         unsigned short* __restrict__ out0,
                         unsigned short* __restrict__ out1) {
    const int lane = threadIdx.x & 63;
    const int wave = threadIdx.x >> 6;
    const int r0 = lane & 15;
    const int g  = lane >> 4;
    const int koff = g << 3;
    const size_t BH = (size_t)B_DIM * H_DIM;
    const int brow = wave * 16 + r0;

    if (blockIdx.x < 64) {
        const int t = s;
        if (t >= T_DIM) return;
        const int n0 = blockIdx.x << 4;
        const unsigned short* hprev = (t == 0) ? hinit : out0 + (size_t)(t - 1) * BH;
        f32x4 acc = (f32x4)(0.f);
        const unsigned short* Ap = hprev + (size_t)brow * H_DIM + koff;
        const unsigned short* Wp = whh0 + (size_t)(n0 + r0) * H_DIM + koff;
        for (int k0 = 0; k0 < H_DIM; k0 += 32)
            acc = __builtin_amdgcn_mfma_f32_16x16x32_bf16(ld_frag(Ap + k0), ld_frag(Wp + k0), acc, 0, 0, 0);
        const int col = n0 + r0;
        unsigned short* o = out0 + (size_t)t * BH;
        const unsigned short* xp = xp0 + (size_t)t * BH;
        for (int r = 0; r < 4; r++) {
            int b = wave * 16 + g * 4 + r;
            float v = tanhf(acc[r] + bf2f(xp[(size_t)b * H_DIM + col]));
            o[(size_t)b * H_DIM + col] = f2bf(v);
        }
    } else {
        const int t = s - 1;
        if (t < 0) return;
        const int n0 = (blockIdx.x - 64) << 4;
        const unsigned short* a0 = out0 + (size_t)t * BH;
        const unsigned short* h1 = (t == 0) ? (hinit + BH) : out1 + (size_t)(t - 1) * BH;
        f32x4 acc = (f32x4)(0.f);
        const unsigned short* Ap0 = a0 + (size_t)brow * H_DIM + koff;
        const unsigned short* Wp0 = wih1 + (size_t)(n0 + r0) * H_DIM + koff;
        const unsigned short* Ap1 = h1 + (size_t)brow * H_DIM + koff;
        const unsigned short* Wp1 = whh1 + (size_t)(n0 + r0) * H_DIM + koff;
        for (int k0 = 0; k0 < H_DIM; k0 += 32)
            acc = __builtin_amdgcn_mfma_f32_16x16x32_bf16(ld_frag(Ap0 + k0), ld_frag(Wp0 + k0), acc, 0, 0, 0);
        for (int k0 = 0; k0 < H_DIM; k0 += 32)
            acc = __builtin_amdgcn_mfma_f32_16x16x32_bf16(ld_frag(Ap1 + k0), ld_frag(Wp1 + k0), acc, 0, 0, 0);
        const int col = n0 + r0;
        unsigned short* o = out1 + (size_t)t * BH;
        for (int r = 0; r < 4; r++) {
            int b = wave * 16 + g * 4 + r;
            float v = tanhf(acc[r] + bias1[col]);
            o[(size_t)b * H_DIM + col] = f2bf(v);
        }
    }
}

// ---------------- launch ----------------
extern "C" void kernel_launch(void* const* d_in, const int* in_sizes, int n_in,
                              void* d_out, int out_size, void* d_ws, size_t ws_size,
                              hipStream_t stream) {
    const float* x      = (const float*)d_in[0];
    const float* hidden = (const float*)d_in[1];
    const float* W_ih0  = (const float*)d_in[2];
    const float* W_hh0  = (const float*)d_in[3];
    const float* b_ih0  = (const float*)d_in[4];
    const float* b_hh0  = (const float*)d_in[5];
    const float* W_ih1  = (const float*)d_in[6];
    const float* W_hh1  = (const float*)d_in[7];
    const float* b_ih1  = (const float*)d_in[8];
    const float* b_hh1  = (const float*)d_in[9];
    const float* W_fc   = (const float*)d_in[10];
    const float* b_fc   = (const float*)d_in[11];

    char* ws = (char*)d_ws;
    size_t off = 0;
    auto alloc = [&](size_t bytes) -> char* {
        char* p = ws + off;
        off += (bytes + 255) & ~(size_t)255;
        return p;
    };
    const size_t TBH = (size_t)T_DIM * B_DIM * H_DIM;  // 33.55M elems
    const size_t TBI = (size_t)T_DIM * B_DIM * I_DIM;  // 16.77M elems

    unsigned short* xb     = (unsigned short*)alloc(TBI * 2);
    unsigned short* wih0b  = (unsigned short*)alloc((size_t)H_DIM * I_DIM * 2);
    unsigned short* whh0b  = (unsigned short*)alloc((size_t)H_DIM * H_DIM * 2);
    unsigned short* wih1b  = (unsigned short*)alloc((size_t)H_DIM * H_DIM * 2);
    unsigned short* whh1b  = (unsigned short*)alloc((size_t)H_DIM * H_DIM * 2);
    unsigned short* wfcb   = (unsigned short*)alloc((size_t)I_DIM * H_DIM * 2);
    unsigned short* hinitb = (unsigned short*)alloc((size_t)2 * B_DIM * H_DIM * 2);
    float* bias0 = (float*)alloc(H_DIM * 4);
    float* bias1 = (float*)alloc(H_DIM * 4);
    unsigned short* xp0    = (unsigned short*)alloc(TBH * 2);
    unsigned short* out0b  = (unsigned short*)alloc(TBH * 2);
    unsigned short* out1b  = (unsigned short*)alloc(TBH * 2);

    auto conv = [&](const float* in, unsigned short* out, int n) {
        int n4 = n / 4;
        int blocks = (n4 + 255) / 256;
        if (blocks > 2048) blocks = 2048;
        conv_f2bf<<<blocks, 256, 0, stream>>>(in, out, n4);
    };
    conv(x, xb, (int)TBI);
    conv(W_ih0, wih0b, H_DIM * I_DIM);
    conv(W_hh0, whh0b, H_DIM * H_DIM);
    conv(W_ih1, wih1b, H_DIM * H_DIM);
    conv(W_hh1, whh1b, H_DIM * H_DIM);
    conv(W_fc, wfcb, I_DIM * H_DIM);
    conv(hidden, hinitb, 2 * B_DIM * H_DIM);
    bias_sum<<<4, 256, 0, stream>>>(b_ih0, b_hh0, bias0, H_DIM);
    bias_sum<<<4, 256, 0, stream>>>(b_ih1, b_hh1, bias1, H_DIM);

    // xp0 = xb @ wih0b^T + (b_ih0 + b_hh0)   [32768 x 1024], K=512, bf16 out
    {
        int M = T_DIM * B_DIM, N = H_DIM, K = I_DIM;
        dim3 grid((M / 64) * (N / 64));
        gemm_bias<1><<<grid, 256, 0, stream>>>(xb, wih0b, bias0, xp0, M, N, K);
    }

    // Pipelined recurrence: layer0 step s, layer1 step s-1.
    for (int s = 0; s <= T_DIM; ++s)
        rnn_step<<<128, 256, 0, stream>>>(s, xp0, whh0b, wih1b, whh1b, bias1,
                                          hinitb, out0b, out1b);

    // out = out1 @ W_fc^T + b_fc   [32768 x 512], K=1024, f32 out
    {
        int M = T_DIM * B_DIM, N = I_DIM, K = H_DIM;
        dim3 grid((M / 64) * (N / 64));
        gemm_bias<0><<<grid, 256, 0, stream>>>(out1b, wfcb, b_fc, d_out, M, N, K);
    }
}

// Round 6
// 7922.178 us; speedup vs baseline: 1.1414x; 1.1414x over previous
//
#include <hip/hip_runtime.h>
#include <stdint.h>

#define T_DIM 512
#define B_DIM 64
#define I_DIM 512
#define H_DIM 1024
#define BH ((size_t)B_DIM * H_DIM)

typedef __attribute__((ext_vector_type(8))) short short8;
typedef __attribute__((ext_vector_type(4))) float f32x4;

__device__ __forceinline__ unsigned short f2bf(float f) {
    unsigned int u = __float_as_uint(f);
    unsigned int r = (u + 0x7FFFu + ((u >> 16) & 1u)) >> 16;
    return (unsigned short)r;
}
__device__ __forceinline__ float bf2f(unsigned short b) {
    return __uint_as_float(((unsigned int)b) << 16);
}
__device__ __forceinline__ float fast_tanh(float x) {
    x = fminf(fmaxf(x, -15.f), 15.f);
    float e = __expf(2.f * x);
    return (e - 1.f) / (e + 1.f);
}

// ---------------- cross-workgroup sync helpers ----------------
__device__ __forceinline__ void wait_group(const int* flags) {
    if (threadIdx.x < 64) {
        while (__hip_atomic_load(&flags[threadIdx.x], __ATOMIC_RELAXED,
                                 __HIP_MEMORY_SCOPE_AGENT) == 0)
            __builtin_amdgcn_s_sleep(2);
        __threadfence();  // acquire: invalidate caches before data reads
    }
    __syncthreads();
}
__device__ __forceinline__ void signal_flag(int* flag) {
    __syncthreads();  // all waves' stores drained (vmcnt 0) before barrier
    if (threadIdx.x == 0) {
        __threadfence();  // release: write back before flag store
        __hip_atomic_store(flag, 1, __ATOMIC_RELAXED, __HIP_MEMORY_SCOPE_AGENT);
    }
}

// ---------------- f32 -> bf16 convert, vectorized x4 ----------------
__global__ void conv_f2bf(const float* __restrict__ in, unsigned short* __restrict__ out, int n4) {
    int i = blockIdx.x * blockDim.x + threadIdx.x;
    int stride = gridDim.x * blockDim.x;
    for (int idx = i; idx < n4; idx += stride) {
        float4 v = reinterpret_cast<const float4*>(in)[idx];
        ushort4 o;
        o.x = f2bf(v.x); o.y = f2bf(v.y); o.z = f2bf(v.z); o.w = f2bf(v.w);
        reinterpret_cast<ushort4*>(out)[idx] = o;
    }
}

__global__ void bias_sum(const float* __restrict__ a, const float* __restrict__ b,
                         float* __restrict__ o, int n) {
    int i = blockIdx.x * blockDim.x + threadIdx.x;
    if (i < n) o[i] = a[i] + b[i];
}

// ---------------- GEMM: C[M,N] = A[M,K] @ W[N,K]^T + bias[N] ----------------
template <int OUT_BF16>
__global__ void gemm_bias(const unsigned short* __restrict__ A,
                          const unsigned short* __restrict__ W,
                          const float* __restrict__ bias,
                          void* __restrict__ Cout,
                          int M, int N, int K) {
    const int ntn = N >> 6;
    const int mt = blockIdx.x / ntn;
    const int nt = blockIdx.x % ntn;
    const int m_base = mt << 6, n_base = nt << 6;
    const int lane = threadIdx.x & 63;
    const int wave = threadIdx.x >> 6;
    const int wm = wave >> 1, wn = wave & 1;
    const int r0 = lane & 15;
    const int g  = lane >> 4;
    const int koff = g << 3;

    f32x4 acc[2][2];
    for (int i = 0; i < 2; i++)
        for (int j = 0; j < 2; j++)
            acc[i][j] = (f32x4)(0.f);

    const unsigned short* Arow0 = A + (size_t)(m_base + wm * 32 + r0) * K + koff;
    const unsigned short* Wrow0 = W + (size_t)(n_base + wn * 32 + r0) * K + koff;

    for (int k0 = 0; k0 < K; k0 += 32) {
        short8 a0 = *reinterpret_cast<const short8*>(Arow0 + k0);
        short8 a1 = *reinterpret_cast<const short8*>(Arow0 + (size_t)16 * K + k0);
        short8 b0 = *reinterpret_cast<const short8*>(Wrow0 + k0);
        short8 b1 = *reinterpret_cast<const short8*>(Wrow0 + (size_t)16 * K + k0);
        acc[0][0] = __builtin_amdgcn_mfma_f32_16x16x32_bf16(a0, b0, acc[0][0], 0, 0, 0);
        acc[0][1] = __builtin_amdgcn_mfma_f32_16x16x32_bf16(a0, b1, acc[0][1], 0, 0, 0);
        acc[1][0] = __builtin_amdgcn_mfma_f32_16x16x32_bf16(a1, b0, acc[1][0], 0, 0, 0);
        acc[1][1] = __builtin_amdgcn_mfma_f32_16x16x32_bf16(a1, b1, acc[1][1], 0, 0, 0);
    }

    for (int mi = 0; mi < 2; mi++) {
        for (int ni = 0; ni < 2; ni++) {
            for (int r = 0; r < 4; r++) {
                int row = m_base + wm * 32 + mi * 16 + g * 4 + r;
                int col = n_base + wn * 32 + ni * 16 + r0;
                float v = acc[mi][ni][r] + bias[col];
                if (OUT_BF16)
                    ((unsigned short*)Cout)[(size_t)row * N + col] = f2bf(v);
                else
                    ((float*)Cout)[(size_t)row * N + col] = v;
            }
        }
    }
}

// ---------------- persistent pipelined 2-layer RNN recurrence ----------------
// 128 wgs x 256 thr, cooperative. wg<64: layer0 (16 cols, W_hh0 slice in LDS).
// wg>=64: layer1 (16 cols, [W_ih1|W_hh1] slice in LDS, K=2048).
// LDS weight layout: 16B chunk (c,kc) at byte (kc*16+c)*16  -> conflict-free
// ds_read_b128 B-fragments (lane addr = g*256 + r0*16 + j*1024).
__global__ void __launch_bounds__(256, 1)
rnn_persist(const unsigned short* __restrict__ xp0,
            const unsigned short* __restrict__ whh0,
            const unsigned short* __restrict__ wih1,
            const unsigned short* __restrict__ whh1,
            const float* __restrict__ bias1,
            const unsigned short* __restrict__ hinit,
            unsigned short* __restrict__ out0,
            unsigned short* __restrict__ out1,
            int* __restrict__ flags0,
            int* __restrict__ flags1)
{
    extern __shared__ char smem[];
    const int lane = threadIdx.x & 63;
    const int wave = threadIdx.x >> 6;
    const int r0 = lane & 15;
    const int g = lane >> 4;
    const int koff = g << 3;
    const int wg = blockIdx.x;
    const int brow = (wave << 4) + r0;

    if (wg < 64) {
        const int n0 = wg << 4;
        // fill LDS: W_hh0 rows [n0, n0+16), chunked
        for (int i = threadIdx.x; i < 2048; i += 256) {
            const int c = i >> 7, kc = i & 127;
            short8 v = *reinterpret_cast<const short8*>(
                whh0 + (size_t)(n0 + c) * H_DIM + (kc << 3));
            *reinterpret_cast<short8*>(smem + ((((kc << 4) + c)) << 4)) = v;
        }
        __syncthreads();
        const int col = n0 + r0;
        const char* Bp = smem + (g << 8) + (r0 << 4);

        for (int t = 0; t < T_DIM; ++t) {
            if (t) wait_group(flags0 + (size_t)(t - 1) * 64);
            const unsigned short* hp = t ? out0 + (size_t)(t - 1) * BH : hinit;
            const unsigned short* Ap = hp + (size_t)brow * H_DIM + koff;
            f32x4 acc[4];
            acc[0] = acc[1] = acc[2] = acc[3] = (f32x4)(0.f);
            short8 ar[16];
            #pragma unroll
            for (int h = 0; h < 2; ++h) {
                #pragma unroll
                for (int i = 0; i < 16; ++i)
                    ar[i] = *reinterpret_cast<const short8*>(Ap + (h << 9) + (i << 5));
                #pragma unroll
                for (int i = 0; i < 16; ++i) {
                    short8 b = *reinterpret_cast<const short8*>(
                        Bp + (size_t)((h << 4) + i) * 1024);
                    acc[i & 3] = __builtin_amdgcn_mfma_f32_16x16x32_bf16(ar[i], b, acc[i & 3], 0, 0, 0);
                }
            }
            f32x4 s = acc[0] + acc[1] + acc[2] + acc[3];
            const unsigned short* xp = xp0 + (size_t)t * BH;
            unsigned short* o = out0 + (size_t)t * BH;
            #pragma unroll
            for (int r = 0; r < 4; ++r) {
                const int row = (wave << 4) + (g << 2) + r;
                float v = fast_tanh(s[r] + bf2f(xp[(size_t)row * H_DIM + col]));
                o[(size_t)row * H_DIM + col] = f2bf(v);
            }
            signal_flag(&flags0[(size_t)t * 64 + wg]);
        }
    } else {
        const int wg2 = wg - 64;
        const int n0 = wg2 << 4;
        // fill LDS: [W_ih1 | W_hh1] rows [n0, n0+16), K=2048, chunked
        for (int i = threadIdx.x; i < 4096; i += 256) {
            const int c = i >> 8, kc = i & 255;
            const unsigned short* src = (kc < 128)
                ? wih1 + (size_t)(n0 + c) * H_DIM + (kc << 3)
                : whh1 + (size_t)(n0 + c) * H_DIM + ((kc - 128) << 3);
            short8 v = *reinterpret_cast<const short8*>(src);
            *reinterpret_cast<short8*>(smem + ((((kc << 4) + c)) << 4)) = v;
        }
        __syncthreads();
        const int col = n0 + r0;
        const float b1 = bias1[col];
        const char* Bp = smem + (g << 8) + (r0 << 4);

        for (int t = 0; t < T_DIM; ++t) {
            wait_group(flags0 + (size_t)t * 64);
            if (t) wait_group(flags1 + (size_t)(t - 1) * 64);
            const unsigned short* a0 = out0 + (size_t)t * BH;
            const unsigned short* h1 = t ? out1 + (size_t)(t - 1) * BH : hinit + BH;
            f32x4 acc[4];
            acc[0] = acc[1] = acc[2] = acc[3] = (f32x4)(0.f);
            short8 ar[16];
            #pragma unroll
            for (int h = 0; h < 4; ++h) {
                const unsigned short* Ap = ((h < 2) ? a0 : h1)
                    + (size_t)brow * H_DIM + koff + ((size_t)(h & 1) << 9);
                #pragma unroll
                for (int i = 0; i < 16; ++i)
                    ar[i] = *reinterpret_cast<const short8*>(Ap + (i << 5));
                #pragma unroll
                for (int i = 0; i < 16; ++i) {
                    short8 b = *reinterpret_cast<const short8*>(
                        Bp + (size_t)((h << 4) + i) * 1024);
                    acc[i & 3] = __builtin_amdgcn_mfma_f32_16x16x32_bf16(ar[i], b, acc[i & 3], 0, 0, 0);
                }
            }
            f32x4 s = acc[0] + acc[1] + acc[2] + acc[3];
            unsigned short* o = out1 + (size_t)t * BH;
            #pragma unroll
            for (int r = 0; r < 4; ++r) {
                const int row = (wave << 4) + (g << 2) + r;
                float v = fast_tanh(s[r] + b1);
                o[(size_t)row * H_DIM + col] = f2bf(v);
            }
            signal_flag(&flags1[(size_t)t * 64 + wg2]);
        }
    }
}

// ---------------- launch ----------------
extern "C" void kernel_launch(void* const* d_in, const int* in_sizes, int n_in,
                              void* d_out, int out_size, void* d_ws, size_t ws_size,
                              hipStream_t stream) {
    const float* x      = (const float*)d_in[0];
    const float* hidden = (const float*)d_in[1];
    const float* W_ih0  = (const float*)d_in[2];
    const float* W_hh0  = (const float*)d_in[3];
    const float* b_ih0  = (const float*)d_in[4];
    const float* b_hh0  = (const float*)d_in[5];
    const float* W_ih1  = (const float*)d_in[6];
    const float* W_hh1  = (const float*)d_in[7];
    const float* b_ih1  = (const float*)d_in[8];
    const float* b_hh1  = (const float*)d_in[9];
    const float* W_fc   = (const float*)d_in[10];
    const float* b_fc   = (const float*)d_in[11];

    char* ws = (char*)d_ws;
    size_t off = 0;
    auto alloc = [&](size_t bytes) -> char* {
        char* p = ws + off;
        off += (bytes + 255) & ~(size_t)255;
        return p;
    };
    const size_t TBH = (size_t)T_DIM * B_DIM * H_DIM;
    const size_t TBI = (size_t)T_DIM * B_DIM * I_DIM;

    unsigned short* xb     = (unsigned short*)alloc(TBI * 2);
    unsigned short* wih0b  = (unsigned short*)alloc((size_t)H_DIM * I_DIM * 2);
    unsigned short* whh0b  = (unsigned short*)alloc((size_t)H_DIM * H_DIM * 2);
    unsigned short* wih1b  = (unsigned short*)alloc((size_t)H_DIM * H_DIM * 2);
    unsigned short* whh1b  = (unsigned short*)alloc((size_t)H_DIM * H_DIM * 2);
    unsigned short* wfcb   = (unsigned short*)alloc((size_t)I_DIM * H_DIM * 2);
    unsigned short* hinitb = (unsigned short*)alloc((size_t)2 * B_DIM * H_DIM * 2);
    float* bias0 = (float*)alloc(H_DIM * 4);
    float* bias1 = (float*)alloc(H_DIM * 4);
    unsigned short* xp0    = (unsigned short*)alloc(TBH * 2);
    unsigned short* out0b  = (unsigned short*)alloc(TBH * 2);
    unsigned short* out1b  = (unsigned short*)alloc(TBH * 2);
    int* flags0 = (int*)alloc((size_t)T_DIM * 64 * 4);   // contiguous with flags1
    int* flags1 = (int*)alloc((size_t)T_DIM * 64 * 4);

    auto conv = [&](const float* in, unsigned short* out, int n) {
        int n4 = n / 4;
        int blocks = (n4 + 255) / 256;
        if (blocks > 2048) blocks = 2048;
        conv_f2bf<<<blocks, 256, 0, stream>>>(in, out, n4);
    };
    conv(x, xb, (int)TBI);
    conv(W_ih0, wih0b, H_DIM * I_DIM);
    conv(W_hh0, whh0b, H_DIM * H_DIM);
    conv(W_ih1, wih1b, H_DIM * H_DIM);
    conv(W_hh1, whh1b, H_DIM * H_DIM);
    conv(W_fc, wfcb, I_DIM * H_DIM);
    conv(hidden, hinitb, 2 * B_DIM * H_DIM);
    bias_sum<<<4, 256, 0, stream>>>(b_ih0, b_hh0, bias0, H_DIM);
    bias_sum<<<4, 256, 0, stream>>>(b_ih1, b_hh1, bias1, H_DIM);

    // zero the sync flags (ws is poisoned 0xAA before every timed call)
    (void)hipMemsetAsync(flags0, 0, (size_t)T_DIM * 64 * 4 * 2, stream);

    // xp0 = xb @ wih0b^T + (b_ih0 + b_hh0)   [32768 x 1024], K=512, bf16 out
    {
        int M = T_DIM * B_DIM, N = H_DIM, K = I_DIM;
        dim3 grid((M / 64) * (N / 64));
        gemm_bias<1><<<grid, 256, 0, stream>>>(xb, wih0b, bias0, xp0, M, N, K);
    }

    // persistent cooperative recurrence (both layers, pipelined via flags)
    {
        void* args[] = {(void*)&xp0, (void*)&whh0b, (void*)&wih1b, (void*)&whh1b,
                        (void*)&bias1, (void*)&hinitb, (void*)&out0b, (void*)&out1b,
                        (void*)&flags0, (void*)&flags1};
        (void)hipLaunchCooperativeKernel(reinterpret_cast<void*>(rnn_persist),
                                         dim3(128), dim3(256), args, 65536, stream);
    }

    // out = out1 @ W_fc^T + b_fc   [32768 x 512], K=1024, f32 out
    {
        int M = T_DIM * B_DIM, N = I_DIM, K = H_DIM;
        dim3 grid((M / 64) * (N / 64));
        gemm_bias<0><<<grid, 256, 0, stream>>>(out1b, wfcb, b_fc, d_out, M, N, K);
    }
}